// Round 4
// baseline (1081.605 us; speedup 1.0000x reference)
//
#include <hip/hip_runtime.h>
#include <cstddef>

// ---------------------------------------------------------------------------
// SegTransformerDecoder — round 4.
// Same as round 3 except sample_k: single-barrier structure, 8 independent
// per-p accumulators (ILP hides L2 latency instead of barrier-fenced chains).
// ---------------------------------------------------------------------------

#define HW   10000
#define WID  100

typedef __attribute__((ext_vector_type(8))) __bf16 bf16x8;
typedef __attribute__((ext_vector_type(4))) float f32x4;
typedef __attribute__((ext_vector_type(4))) unsigned int uint4v;

__device__ __forceinline__ float gelu_exact(float x) {
    return 0.5f * x * (1.0f + erff(x * 0.7071067811865475f));
}
__device__ __forceinline__ unsigned short f2bf(float v) {
    unsigned int b = __float_as_uint(v);
    return (unsigned short)((b + 0x7FFFu + ((b >> 16) & 1u)) >> 16);
}
__device__ __forceinline__ bf16x8 load_frag(const short* p) {
    return __builtin_bit_cast(bf16x8, *(const uint4v*)p);
}

// ---------------------------------------------------------------------------
// fp32 implicit-GEMM conv 5x5 (decision chain — must stay fp32).
// ---------------------------------------------------------------------------
__global__ __launch_bounds__(256)
void conv1_f32(const float* __restrict__ wpkf, const float* __restrict__ xpad,
               float* __restrict__ slab)
{
    __shared__ float As[16 * 128];
    __shared__ float Bs[16 * 68];
    const int t  = threadIdx.x;
    const int og = t >> 4, pg = t & 15;
    const int x0 = blockIdx.x * 32, y0 = blockIdx.y * 2;
    const int z  = blockIdx.z;
    const int ky_lo = z * 2;
    const int ky_hi = (ky_lo + 2 < 5) ? ky_lo + 2 : 5;

    const int cpix = t >> 2;
    const int cpy = cpix >> 5, cpx = cpix & 31;
    const int cj  = (t & 3) * 4;

    float acc[8][4];
#pragma unroll
    for (int i = 0; i < 8; ++i)
#pragma unroll
        for (int j = 0; j < 4; ++j) acc[i][j] = 0.f;

    for (int ky = ky_lo; ky < ky_hi; ++ky) {
        for (int kx = 0; kx < 5; ++kx) {
            for (int ic0 = 0; ic0 < 128; ic0 += 16) {
                __syncthreads();
                const float* asrc = wpkf + (size_t)((ky * 5 + kx) * 128 + ic0) * 128;
                *(float4*)(As + t * 8)     = *(const float4*)(asrc + t * 8);
                *(float4*)(As + t * 8 + 4) = *(const float4*)(asrc + t * 8 + 4);
                const float* bsrc = xpad +
                    (size_t)((y0 + cpy + ky) * 104 + x0 + cpx + kx) * 128 + ic0 + cj;
                const float4 bv = *(const float4*)bsrc;
                Bs[(cj + 0) * 68 + cpix] = bv.x;
                Bs[(cj + 1) * 68 + cpix] = bv.y;
                Bs[(cj + 2) * 68 + cpix] = bv.z;
                Bs[(cj + 3) * 68 + cpix] = bv.w;
                __syncthreads();
#pragma unroll
                for (int k = 0; k < 16; ++k) {
                    float a[8], b[4];
                    *(float4*)a       = *(float4*)(As + k * 128 + og * 8);
                    *(float4*)(a + 4) = *(float4*)(As + k * 128 + og * 8 + 4);
                    *(float4*)b       = *(float4*)(Bs + k * 68 + pg * 4);
#pragma unroll
                    for (int i = 0; i < 8; ++i)
#pragma unroll
                        for (int j = 0; j < 4; ++j)
                            acc[i][j] = fmaf(a[i], b[j], acc[i][j]);
                }
            }
        }
    }

    float* sl = slab + (size_t)z * 1280000;
#pragma unroll
    for (int j = 0; j < 4; ++j) {
        const int p  = pg * 4 + j;
        const int gx = x0 + (p & 31);
        const int gy = y0 + (p >> 5);
        if (gx >= 100) continue;
        const int pix = gy * WID + gx;
#pragma unroll
        for (int i = 0; i < 8; ++i)
            sl[(size_t)(og * 8 + i) * HW + pix] = acc[i][j];
    }
}

// ---------------------------------------------------------------------------
// bf16 MFMA implicit-GEMM conv (unchanged from round 3).
// ---------------------------------------------------------------------------
template<int CIN, int KS, int COUT, int EPI, bool ACT, int OPAD, int OPW, int KSPLIT>
__global__ __launch_bounds__(256)
void mfma_conv(const short* __restrict__ wpk, const short* __restrict__ xcl,
               const float* __restrict__ bias,
               float* __restrict__ outcm, short* __restrict__ outcl)
{
    constexpr int PW = 100 + 2 * (KS / 2);
    constexpr int CHUNK = (KS + KSPLIT - 1) / KSPLIT;
    const int lane = threadIdx.x & 63;
    const int wave = threadIdx.x >> 6;
    const int wm = (wave >> 1) * 32;
    const int wn = (wave & 1) * 64;
    const int lq = lane >> 4;
    const int ln = lane & 15;

    const int oc0 = blockIdx.x * 64;
    const int y0  = blockIdx.y * 4;
    const int zb  = blockIdx.z;
    const int bx  = (KSPLIT > 1) ? (zb & 3) : zb;
    const int ks  = (KSPLIT > 1) ? (zb >> 2) : 0;
    const int x0  = bx * 32;
    const int ky_lo = ks * CHUNK;
    const int ky_hi = (ky_lo + CHUNK < KS) ? ky_lo + CHUNK : KS;

    int bpix[4];
#pragma unroll
    for (int nt = 0; nt < 4; ++nt) {
        const int nl = wn + nt * 16 + ln;
        bpix[nt] = (y0 + (nl >> 5)) * PW + (x0 + (nl & 31));
    }

    f32x4 acc[2][4];
#pragma unroll
    for (int mt = 0; mt < 2; ++mt)
#pragma unroll
        for (int nt = 0; nt < 4; ++nt)
#pragma unroll
            for (int r = 0; r < 4; ++r) acc[mt][nt][r] = 0.f;

    const int arow0 = oc0 + wm + ln;

    for (int ky = ky_lo; ky < ky_hi; ++ky) {
#pragma unroll
        for (int kx = 0; kx < KS; ++kx) {
            const short* wsl = wpk + (size_t)((ky * KS + kx) * COUT) * CIN;
            const short* xsl = xcl + (size_t)(ky * PW + kx) * CIN;
            for (int ic0 = 0; ic0 < CIN; ic0 += 32) {
                bf16x8 a[2], b[4];
#pragma unroll
                for (int mt = 0; mt < 2; ++mt)
                    a[mt] = load_frag(wsl + (size_t)(arow0 + mt * 16) * CIN + ic0 + lq * 8);
#pragma unroll
                for (int nt = 0; nt < 4; ++nt)
                    b[nt] = load_frag(xsl + (size_t)bpix[nt] * CIN + ic0 + lq * 8);
#pragma unroll
                for (int mt = 0; mt < 2; ++mt)
#pragma unroll
                    for (int nt = 0; nt < 4; ++nt)
                        acc[mt][nt] = __builtin_amdgcn_mfma_f32_16x16x32_bf16(
                            a[mt], b[nt], acc[mt][nt], 0, 0, 0);
            }
        }
    }

#pragma unroll
    for (int mt = 0; mt < 2; ++mt) {
        const int ocr = oc0 + wm + mt * 16 + lq * 4;
        float bb[4];
        if (EPI == 1) {
            const float4 bv = *(const float4*)(bias + ocr);
            bb[0] = bv.x; bb[1] = bv.y; bb[2] = bv.z; bb[3] = bv.w;
        }
#pragma unroll
        for (int nt = 0; nt < 4; ++nt) {
            const int nl = wn + nt * 16 + ln;
            const int x = x0 + (nl & 31);
            const int y = y0 + (nl >> 5);
            if (x >= 100) continue;
            if (EPI == 1) {
                float v[4];
#pragma unroll
                for (int r = 0; r < 4; ++r) {
                    float t = acc[mt][nt][r] + bb[r];
                    if (ACT) t = gelu_exact(t);
                    v[r] = t;
                }
                ushort4 pk;
                pk.x = f2bf(v[0]); pk.y = f2bf(v[1]); pk.z = f2bf(v[2]); pk.w = f2bf(v[3]);
                *(ushort4*)(outcl + ((size_t)(y + OPAD) * OPW + (x + OPAD)) * COUT + ocr) = pk;
            } else {
                const int pix = y * WID + x;
#pragma unroll
                for (int r = 0; r < 4; ++r)
                    outcm[((size_t)ks * COUT + ocr + r) * HW + pix] = acc[mt][nt][r];
            }
        }
    }
}

// out = bias + res + slab0 + slab1 + slab2   (128 x HW)
__global__ void reduce3_k(const float* __restrict__ bias, const float* __restrict__ res,
                          const float* __restrict__ slab, float* __restrict__ out)
{
    const int i = blockIdx.x * blockDim.x + threadIdx.x;
    if (i >= 128 * HW) return;
    const int c = i / HW;
    out[i] = bias[c] + res[i] + slab[i] + slab[1280000 + i] + slab[2560000 + i];
}

__global__ void pad_cl_f32(const float* __restrict__ in, float* __restrict__ out)
{
    const int total = 104 * 104 * 128;
    for (int i = blockIdx.x * blockDim.x + threadIdx.x; i < total; i += gridDim.x * blockDim.x) {
        const int c = i % 128;
        const int p = i / 128;
        const int x = p % 104 - 2;
        const int y = p / 104 - 2;
        float v = 0.f;
        if (x >= 0 && x < 100 && y >= 0 && y < 100) v = in[(size_t)c * HW + y * WID + x];
        out[i] = v;
    }
}

template<int C, int PAD>
__global__ void pad_cl_cast(const float* __restrict__ in, short* __restrict__ out)
{
    constexpr int PW = 100 + 2 * PAD;
    const int total = PW * PW * C;
    for (int i = blockIdx.x * blockDim.x + threadIdx.x; i < total; i += gridDim.x * blockDim.x) {
        const int c = i % C;
        const int p = i / C;
        const int x = p % PW - PAD;
        const int y = p / PW - PAD;
        float v = 0.f;
        if (x >= 0 && x < 100 && y >= 0 && y < 100) v = in[(size_t)c * HW + y * WID + x];
        out[i] = (short)f2bf(v);
    }
}

template<int OC, int CI, int KS>
__global__ void pack_w(const float* __restrict__ w, short* __restrict__ out)
{
    const int total = OC * CI * KS * KS;
    for (int i = blockIdx.x * blockDim.x + threadIdx.x; i < total; i += gridDim.x * blockDim.x) {
        const int ic = i % CI;
        int t = i / CI;
        const int oc = t % OC;
        const int s = t / OC;
        const int ky = s / KS, kx = s % KS;
        out[i] = (short)f2bf(w[(((size_t)oc * CI + ic) * KS + ky) * KS + kx]);
    }
}

__global__ void pack_w1_f32(const float* __restrict__ w, float* __restrict__ out)
{
    const int total = 128 * 128 * 25;
    for (int i = blockIdx.x * blockDim.x + threadIdx.x; i < total; i += gridDim.x * blockDim.x) {
        const int oc = i % 128;
        int t = i / 128;
        const int ic = t % 128;
        const int s = t / 128;
        const int ky = s / 5, kx = s % 5;
        out[i] = w[(((size_t)oc * 128 + ic) * 5 + ky) * 5 + kx];
    }
}

__global__ void inorm_k(const float* __restrict__ in, float* __restrict__ out)
{
    const int c = blockIdx.x;
    const float* p = in + (size_t)c * HW;
    __shared__ float red[256];
    const int tid = threadIdx.x;

    float s = 0.f;
    for (int i = tid; i < HW; i += 256) s += p[i];
    red[tid] = s; __syncthreads();
    for (int o = 128; o > 0; o >>= 1) { if (tid < o) red[tid] += red[tid + o]; __syncthreads(); }
    const float mean = red[0] * 1e-4f;
    __syncthreads();

    float v = 0.f;
    for (int i = tid; i < HW; i += 256) { const float d = p[i] - mean; v += d * d; }
    red[tid] = v; __syncthreads();
    for (int o = 128; o > 0; o >>= 1) { if (tid < o) red[tid] += red[tid + o]; __syncthreads(); }
    const float rstd = rsqrtf(red[0] * 1e-4f + 1e-5f);

    float* op = out + (size_t)c * HW;
    for (int i = tid; i < HW; i += 256) op[i] = (p[i] - mean) * rstd;
}

__global__ void offsw_k(const float* __restrict__ qn, const float* __restrict__ bev_pos,
                        const float* __restrict__ off_w, const float* __restrict__ off_b,
                        const float* __restrict__ sw_w, const float* __restrict__ sw_b,
                        float* __restrict__ refp, float* __restrict__ swts)
{
    const int pix = blockIdx.x;
    const int tid = threadIdx.x;
    __shared__ float qv[128];
    __shared__ float swraw[32];
    qv[tid]      = qn[(size_t)tid * HW + pix];
    qv[tid + 64] = qn[(size_t)(tid + 64) * HW + pix];
    __syncthreads();

    if (tid < 24) {
        float acc = off_b[tid];
        for (int c = 0; c < 128; ++c) acc = fmaf(qv[c], off_w[tid * 128 + c], acc);
        const float s = 1.0f / (1.0f + expf(-acc));
        const int coord = tid % 3;
        const float rng = (coord < 2) ? 0.250001f : 4.000001f;
        const float v = s * rng * 2.0f - rng;
        const float lo[3]   = {-50.f, -50.f, -5.f};
        const float span[3] = {100.f, 100.f, 8.f};
        refp[pix * 24 + tid] = bev_pos[pix * 3 + coord] * span[coord] + lo[coord] + v;
    } else if (tid >= 32) {
        const int j = tid - 32;
        float acc = sw_b[j];
        for (int c = 0; c < 128; ++c) acc = fmaf(qv[c], sw_w[j * 128 + c], acc);
        swraw[j] = acc;
    }
    __syncthreads();
    if (tid < 8) {
        float m = -1e30f;
#pragma unroll
        for (int l = 0; l < 4; ++l) m = fmaxf(m, swraw[tid * 4 + l]);
        float e[4], sum = 0.f;
#pragma unroll
        for (int l = 0; l < 4; ++l) { e[l] = expf(swraw[tid * 4 + l] - m); sum += e[l]; }
        const float inv = 1.0f / sum;
#pragma unroll
        for (int l = 0; l < 4; ++l) swts[pix * 32 + tid * 4 + l] = e[l] * inv;
    }
}

__global__ void transpose_feat_k(const float* __restrict__ in, float* __restrict__ out,
                                 int Hl, int Wl)
{
    const int total = 6 * 132 * Hl * Wl;
    for (int i = blockIdx.x * blockDim.x + threadIdx.x; i < total; i += gridDim.x * blockDim.x) {
        int c = i % 132;
        int t = i / 132;
        const int x = t % Wl; t /= Wl;
        const int y = t % Hl; t /= Hl;
        const int n = t;
        out[i] = in[(((size_t)n * 132 + c) * Hl + y) * Wl + x];
    }
}

// ---------------------------------------------------------------------------
// sample_k round 4: single barrier pair; acc[8]/accT[8] in registers so all
// tap loads across the whole (p,n,l) nest can be pipelined by the compiler.
// ---------------------------------------------------------------------------
__global__ __launch_bounds__(128)
void sample_k(const float* __restrict__ refp, const float* __restrict__ swts,
              const float* __restrict__ l2i,
              const float* __restrict__ fT0, const float* __restrict__ fT1,
              const float* __restrict__ fT2, const float* __restrict__ fT3,
              short* __restrict__ sfo)
{
    const int pix = blockIdx.x;
    const int tid = threadIdx.x;                   // 128
    __shared__ float rp[24], sw[32], M[96], tail[32];
    if (tid < 24) rp[tid] = refp[pix * 24 + tid];
    if (tid < 32) sw[tid] = swts[pix * 32 + tid];
    if (tid < 96) M[tid]  = l2i[tid];
    __syncthreads();

    const float* fT[4] = {fT0, fT1, fT2, fT3};
    const int HL[4] = {32, 16, 8, 4};
    const int WL[4] = {88, 44, 22, 11};

    float acc[8], accT[8];
#pragma unroll
    for (int p = 0; p < 8; ++p) { acc[p] = 0.f; accT[p] = 0.f; }

    for (int p = 0; p < 8; ++p) {
        const float X = rp[p * 3], Y = rp[p * 3 + 1], Z = rp[p * 3 + 2];
        for (int n = 0; n < 6; ++n) {
            const float* m = M + n * 16;
            const float cx = m[0] * X + m[1] * Y + m[2]  * Z + m[3];
            const float cy = m[4] * X + m[5] * Y + m[6]  * Z + m[7];
            const float cz = m[8] * X + m[9] * Y + m[10] * Z + m[11];
            const bool valid = cz > 1e-5f;
            const float zz = fmaxf(cz, 1e-5f);
            const float gx = valid ? (cx / zz) * (2.0f / 704.0f) - 1.0f : -2.0f;
            const float gy = valid ? (cy / zz) * (2.0f / 256.0f) - 1.0f : -2.0f;
#pragma unroll
            for (int l = 0; l < 4; ++l) {
                const float wl = sw[p * 4 + l];
                const int Hl = HL[l], Wl = WL[l];
                const float fx = (gx + 1.0f) * 0.5f * (float)Wl - 0.5f;
                const float fy = (gy + 1.0f) * 0.5f * (float)Hl - 0.5f;
                if (!(fx >= -1.0f && fx < (float)Wl && fy >= -1.0f && fy < (float)Hl))
                    continue;
                const float x0f = floorf(fx), y0f = floorf(fy);
                const int x0 = (int)x0f, y0 = (int)y0f;
                const int x1 = x0 + 1, y1 = y0 + 1;
                const float wx1 = fx - x0f, wy1 = fy - y0f;
                const float wx0 = 1.0f - wx1, wy0 = 1.0f - wy1;
                const bool okx0 = (x0 >= 0), okx1 = (x1 < Wl);
                const bool oky0 = (y0 >= 0), oky1 = (y1 < Hl);
                const float* fb = fT[l] + (size_t)n * Hl * Wl * 132;
                if (okx0 && oky0) {
                    const float wt = wx0 * wy0 * wl;
                    const float* tp = fb + (size_t)(y0 * Wl + x0) * 132;
                    acc[p] = fmaf(tp[tid], wt, acc[p]);
                    if (tid < 4) accT[p] = fmaf(tp[128 + tid], wt, accT[p]);
                }
                if (okx1 && oky0) {
                    const float wt = wx1 * wy0 * wl;
                    const float* tp = fb + (size_t)(y0 * Wl + x1) * 132;
                    acc[p] = fmaf(tp[tid], wt, acc[p]);
                    if (tid < 4) accT[p] = fmaf(tp[128 + tid], wt, accT[p]);
                }
                if (okx0 && oky1) {
                    const float wt = wx0 * wy1 * wl;
                    const float* tp = fb + (size_t)(y1 * Wl + x0) * 132;
                    acc[p] = fmaf(tp[tid], wt, acc[p]);
                    if (tid < 4) accT[p] = fmaf(tp[128 + tid], wt, accT[p]);
                }
                if (okx1 && oky1) {
                    const float wt = wx1 * wy1 * wl;
                    const float* tp = fb + (size_t)(y1 * Wl + x1) * 132;
                    acc[p] = fmaf(tp[tid], wt, acc[p]);
                    if (tid < 4) accT[p] = fmaf(tp[128 + tid], wt, accT[p]);
                }
            }
        }
    }

    if (tid < 4) {
#pragma unroll
        for (int p = 0; p < 8; ++p) tail[p * 4 + tid] = accT[p];
    }
    __syncthreads();

    float sf1 = 0.f, sf2 = 0.f;
#pragma unroll
    for (int p = 0; p < 8; ++p) {
        const float dx = rp[p * 3]     - tail[p * 4 + 0];
        const float dy = rp[p * 3 + 1] - tail[p * 4 + 1];
        const float dz = rp[p * 3 + 2] - tail[p * 4 + 2];
        const float wgt = expf(-0.1f * (dx * dx + dy * dy + dz * dz));
        sf1 += acc[p];
        sf2 += acc[p] * wgt;
    }
    const int y = pix / WID, x = pix % WID;
    const size_t po = ((size_t)(y + 1) * 102 + (x + 1)) * 256;
    sfo[po + tid]       = (short)f2bf(sf1);
    sfo[po + 128 + tid] = (short)f2bf(sf2);
}

// ---------------------------------------------------------------------------

extern "C" void kernel_launch(void* const* d_in, const int* in_sizes, int n_in,
                              void* d_out, int out_size, void* d_ws, size_t ws_size,
                              hipStream_t stream)
{
    const float* bev_query = (const float*)d_in[0];
    const float* bev_pos   = (const float*)d_in[1];
    const float* l2i       = (const float*)d_in[2];
    const float* feat0     = (const float*)d_in[3];
    const float* feat1     = (const float*)d_in[4];
    const float* feat2     = (const float*)d_in[5];
    const float* feat3     = (const float*)d_in[6];
    const float* in_w      = (const float*)d_in[7];
    const float* in_b      = (const float*)d_in[8];
    const float* off_w     = (const float*)d_in[9];
    const float* off_b     = (const float*)d_in[10];
    const float* sw_w      = (const float*)d_in[11];
    const float* sw_b      = (const float*)d_in[12];
    const float* mid_w1    = (const float*)d_in[13];
    const float* mid_b1    = (const float*)d_in[14];
    const float* mid_w2    = (const float*)d_in[15];
    const float* mid_b2    = (const float*)d_in[16];
    const float* mid_w3    = (const float*)d_in[17];
    const float* mid_b3    = (const float*)d_in[18];
    const float* out_w     = (const float*)d_in[19];
    const float* out_b     = (const float*)d_in[20];
    float* out = (float*)d_out;

    float* ws    = (float*)d_ws;
    float* qn    = ws;                        // 1,280,000 f
    float* tmp   = qn + 1280000;              // 1,280,000 f
    float* refp  = tmp + 1280000;             //   240,000 f
    float* swts  = refp + 240000;             //   320,000 f
    float* slab  = swts + 320000;             // 3,840,000 f  (3 K-split slabs; fT alias)
    float* wpk1f = slab + 3840000;            //   409,600 f
    short* m1U   = (short*)(wpk1f + 409600);  // 5,130,000 sh
    short* m2U   = m1U + 5130000;             // 5,345,000 sh
    short* wp_m1 = m2U + 5345000;             // 1,179,648 sh
    short* wp_m2 = wp_m1 + 1179648;           //   262,144 sh
    short* wp_m3 = wp_m2 + 262144;            //   589,824 sh
    short* wp_out= wp_m3 + 589824;            //   409,600 sh

    float* fT0 = slab;
    float* fT1 = fT0 + 6 * 132 * 32 * 88;
    float* fT2 = fT1 + 6 * 132 * 16 * 44;
    float* fT3 = fT2 + 6 * 132 * 8  * 22;
    float* xpadf = (float*)m1U;
    short* m1_cl = m1U;
    short* q2pad = m1U;
    short* sf_cl = m2U;
    short* m2_cl = m2U;

    const dim3 blk(256);

    // ---- weight packing ----
    hipLaunchKernelGGL(pack_w1_f32, dim3(1600), blk, 0, stream, in_w, wpk1f);
    hipLaunchKernelGGL((pack_w<512, 256, 3>), dim3(4608), blk, 0, stream, mid_w1, wp_m1);
    hipLaunchKernelGGL((pack_w<512, 512, 1>), dim3(1024), blk, 0, stream, mid_w2, wp_m2);
    hipLaunchKernelGGL((pack_w<128, 512, 3>), dim3(2304), blk, 0, stream, mid_w3, wp_m3);
    hipLaunchKernelGGL((pack_w<128, 128, 5>), dim3(1600), blk, 0, stream, out_w, wp_out);

    // ---- 1. q1 = bev_query + conv5x5_f32(bev_query) ----
    hipLaunchKernelGGL(pad_cl_f32, dim3(5411), blk, 0, stream, bev_query, xpadf);
    hipLaunchKernelGGL(conv1_f32, dim3(4, 50, 3), blk, 0, stream, wpk1f, xpadf, slab);
    hipLaunchKernelGGL(reduce3_k, dim3(5000), blk, 0, stream, in_b, bev_query, slab, tmp);
    // ---- 2. qn = inorm(q1) ----
    hipLaunchKernelGGL(inorm_k, dim3(128), blk, 0, stream, tmp, qn);
    // ---- 3. ref points + softmax weights (fp32) ----
    hipLaunchKernelGGL(offsw_k, dim3(HW), dim3(64), 0, stream,
                       qn, bev_pos, off_w, off_b, sw_w, sw_b, refp, swts);
    // ---- 4. feature transposes ----
    hipLaunchKernelGGL(transpose_feat_k, dim3(8713), blk, 0, stream, feat0, fT0, 32, 88);
    hipLaunchKernelGGL(transpose_feat_k, dim3(2179), blk, 0, stream, feat1, fT1, 16, 44);
    hipLaunchKernelGGL(transpose_feat_k, dim3(545),  blk, 0, stream, feat2, fT2, 8, 22);
    hipLaunchKernelGGL(transpose_feat_k, dim3(137),  blk, 0, stream, feat3, fT3, 4, 11);
    // ---- 5. sampling -> sf_cl bf16 padded(1) ----
    hipMemsetAsync(sf_cl, 0, (size_t)2663424 * 2, stream);
    hipLaunchKernelGGL(sample_k, dim3(HW), dim3(128), 0, stream,
                       refp, swts, l2i, fT0, fT1, fT2, fT3, sf_cl);
    // ---- 6. m1 = gelu(conv3x3 256->512) ----
    hipLaunchKernelGGL((mfma_conv<256, 3, 512, 1, true, 0, 100, 1>), dim3(8, 25, 4), blk, 0, stream,
                       wp_m1, sf_cl, mid_b1, nullptr, m1_cl);
    // ---- 7. m2 = gelu(conv1x1 512->512) -> m2_cl padded(1) ----
    hipMemsetAsync(m2U, 0, (size_t)5326848 * 2, stream);
    hipLaunchKernelGGL((mfma_conv<512, 1, 512, 1, true, 1, 102, 1>), dim3(8, 25, 4), blk, 0, stream,
                       wp_m2, m1_cl, mid_b2, nullptr, m2_cl);
    // ---- 8. q2 = qn + conv3x3 512->128  (K-split 3, slabs) ----
    hipLaunchKernelGGL((mfma_conv<512, 3, 128, 2, false, 0, 0, 3>), dim3(2, 25, 12), blk, 0, stream,
                       wp_m3, m2_cl, mid_b3, slab, nullptr);
    hipLaunchKernelGGL(reduce3_k, dim3(5000), blk, 0, stream, mid_b3, qn, slab, tmp);
    // ---- 9. q2n = inorm(q2) ----
    hipLaunchKernelGGL(inorm_k, dim3(128), blk, 0, stream, tmp, qn);
    // ---- 10. q3 = q2n + conv5x5 bf16 (K-split 3, slabs) ----
    hipLaunchKernelGGL((pad_cl_cast<128, 2>), dim3(5411), blk, 0, stream, qn, q2pad);
    hipLaunchKernelGGL((mfma_conv<128, 5, 128, 2, false, 0, 0, 3>), dim3(2, 25, 12), blk, 0, stream,
                       wp_out, q2pad, out_b, slab, nullptr);
    hipLaunchKernelGGL(reduce3_k, dim3(5000), blk, 0, stream, out_b, qn, slab, tmp);
    // ---- 11. out = inorm(q3) ----
    hipLaunchKernelGGL(inorm_k, dim3(128), blk, 0, stream, tmp, out);
}

// Round 5
// 906.457 us; speedup vs baseline: 1.1932x; 1.1932x over previous
//
#include <hip/hip_runtime.h>
#include <cstddef>

// ---------------------------------------------------------------------------
// SegTransformerDecoder — round 5.
// Changes vs round 4:
//  * sampling split: proj_k (1 wave/pix) computes+compacts valid (gx,gy)
//    records per p (ballot prefix, deterministic n-order); sample_k only
//    loops valid records — removes ~60% duplicated VALU work.
//  * mfma_conv tile 64x128 -> 128x128 (4mt x 4nt per wave): 8 loads per
//    16 MFMAs instead of 6 per 8 — 2x arithmetic intensity.
// ---------------------------------------------------------------------------

#define HW   10000
#define WID  100

typedef __attribute__((ext_vector_type(8))) __bf16 bf16x8;
typedef __attribute__((ext_vector_type(4))) float f32x4;
typedef __attribute__((ext_vector_type(4))) unsigned int uint4v;

__device__ __forceinline__ float gelu_exact(float x) {
    return 0.5f * x * (1.0f + erff(x * 0.7071067811865475f));
}
__device__ __forceinline__ unsigned short f2bf(float v) {
    unsigned int b = __float_as_uint(v);
    return (unsigned short)((b + 0x7FFFu + ((b >> 16) & 1u)) >> 16);
}
__device__ __forceinline__ bf16x8 load_frag(const short* p) {
    return __builtin_bit_cast(bf16x8, *(const uint4v*)p);
}

// ---------------------------------------------------------------------------
// fp32 implicit-GEMM conv 5x5 (decision chain — must stay fp32). Unchanged.
// ---------------------------------------------------------------------------
__global__ __launch_bounds__(256)
void conv1_f32(const float* __restrict__ wpkf, const float* __restrict__ xpad,
               float* __restrict__ slab)
{
    __shared__ float As[16 * 128];
    __shared__ float Bs[16 * 68];
    const int t  = threadIdx.x;
    const int og = t >> 4, pg = t & 15;
    const int x0 = blockIdx.x * 32, y0 = blockIdx.y * 2;
    const int z  = blockIdx.z;
    const int ky_lo = z * 2;
    const int ky_hi = (ky_lo + 2 < 5) ? ky_lo + 2 : 5;

    const int cpix = t >> 2;
    const int cpy = cpix >> 5, cpx = cpix & 31;
    const int cj  = (t & 3) * 4;

    float acc[8][4];
#pragma unroll
    for (int i = 0; i < 8; ++i)
#pragma unroll
        for (int j = 0; j < 4; ++j) acc[i][j] = 0.f;

    for (int ky = ky_lo; ky < ky_hi; ++ky) {
        for (int kx = 0; kx < 5; ++kx) {
            for (int ic0 = 0; ic0 < 128; ic0 += 16) {
                __syncthreads();
                const float* asrc = wpkf + (size_t)((ky * 5 + kx) * 128 + ic0) * 128;
                *(float4*)(As + t * 8)     = *(const float4*)(asrc + t * 8);
                *(float4*)(As + t * 8 + 4) = *(const float4*)(asrc + t * 8 + 4);
                const float* bsrc = xpad +
                    (size_t)((y0 + cpy + ky) * 104 + x0 + cpx + kx) * 128 + ic0 + cj;
                const float4 bv = *(const float4*)bsrc;
                Bs[(cj + 0) * 68 + cpix] = bv.x;
                Bs[(cj + 1) * 68 + cpix] = bv.y;
                Bs[(cj + 2) * 68 + cpix] = bv.z;
                Bs[(cj + 3) * 68 + cpix] = bv.w;
                __syncthreads();
#pragma unroll
                for (int k = 0; k < 16; ++k) {
                    float a[8], b[4];
                    *(float4*)a       = *(float4*)(As + k * 128 + og * 8);
                    *(float4*)(a + 4) = *(float4*)(As + k * 128 + og * 8 + 4);
                    *(float4*)b       = *(float4*)(Bs + k * 68 + pg * 4);
#pragma unroll
                    for (int i = 0; i < 8; ++i)
#pragma unroll
                        for (int j = 0; j < 4; ++j)
                            acc[i][j] = fmaf(a[i], b[j], acc[i][j]);
                }
            }
        }
    }

    float* sl = slab + (size_t)z * 1280000;
#pragma unroll
    for (int j = 0; j < 4; ++j) {
        const int p  = pg * 4 + j;
        const int gx = x0 + (p & 31);
        const int gy = y0 + (p >> 5);
        if (gx >= 100) continue;
        const int pix = gy * WID + gx;
#pragma unroll
        for (int i = 0; i < 8; ++i)
            sl[(size_t)(og * 8 + i) * HW + pix] = acc[i][j];
    }
}

// ---------------------------------------------------------------------------
// bf16 MFMA implicit-GEMM conv, 128oc x 128pix block tile (4 waves 2x2,
// 4mt x 4nt per wave). grid = (COUT/128, 25, 4*KSPLIT).
// ---------------------------------------------------------------------------
template<int CIN, int KS, int COUT, int EPI, bool ACT, int OPAD, int OPW, int KSPLIT>
__global__ __launch_bounds__(256)
void mfma_conv(const short* __restrict__ wpk, const short* __restrict__ xcl,
               const float* __restrict__ bias,
               float* __restrict__ outcm, short* __restrict__ outcl)
{
    constexpr int PW = 100 + 2 * (KS / 2);
    constexpr int CHUNK = (KS + KSPLIT - 1) / KSPLIT;
    const int lane = threadIdx.x & 63;
    const int wave = threadIdx.x >> 6;
    const int wr = wave >> 1;            // oc half (0/1) -> +wr*64
    const int wc = wave & 1;             // pix half (0/1) -> +wc*64
    const int lq = lane >> 4;
    const int ln = lane & 15;

    const int oc0 = blockIdx.x * 128;
    const int y0  = blockIdx.y * 4;
    const int zb  = blockIdx.z;
    const int bx  = (KSPLIT > 1) ? (zb & 3) : zb;
    const int ks  = (KSPLIT > 1) ? (zb >> 2) : 0;
    const int x0  = bx * 32;
    const int ky_lo = ks * CHUNK;
    const int ky_hi = (ky_lo + CHUNK < KS) ? ky_lo + CHUNK : KS;

    int bpix[4];
#pragma unroll
    for (int nt = 0; nt < 4; ++nt) {
        const int nl = wc * 64 + nt * 16 + ln;
        bpix[nt] = (y0 + (nl >> 5)) * PW + (x0 + (nl & 31));
    }

    f32x4 acc[4][4];
#pragma unroll
    for (int mt = 0; mt < 4; ++mt)
#pragma unroll
        for (int nt = 0; nt < 4; ++nt)
#pragma unroll
            for (int r = 0; r < 4; ++r) acc[mt][nt][r] = 0.f;

    const int arow0 = oc0 + wr * 64 + ln;

    for (int ky = ky_lo; ky < ky_hi; ++ky) {
#pragma unroll
        for (int kx = 0; kx < KS; ++kx) {
            const short* wsl = wpk + (size_t)((ky * KS + kx) * COUT) * CIN;
            const short* xsl = xcl + (size_t)(ky * PW + kx) * CIN;
            for (int ic0 = 0; ic0 < CIN; ic0 += 32) {
                bf16x8 a[4], b[4];
#pragma unroll
                for (int mt = 0; mt < 4; ++mt)
                    a[mt] = load_frag(wsl + (size_t)(arow0 + mt * 16) * CIN + ic0 + lq * 8);
#pragma unroll
                for (int nt = 0; nt < 4; ++nt)
                    b[nt] = load_frag(xsl + (size_t)bpix[nt] * CIN + ic0 + lq * 8);
#pragma unroll
                for (int mt = 0; mt < 4; ++mt)
#pragma unroll
                    for (int nt = 0; nt < 4; ++nt)
                        acc[mt][nt] = __builtin_amdgcn_mfma_f32_16x16x32_bf16(
                            a[mt], b[nt], acc[mt][nt], 0, 0, 0);
            }
        }
    }

#pragma unroll
    for (int mt = 0; mt < 4; ++mt) {
        const int ocr = oc0 + wr * 64 + mt * 16 + lq * 4;
        float bb[4];
        if (EPI == 1) {
            const float4 bv = *(const float4*)(bias + ocr);
            bb[0] = bv.x; bb[1] = bv.y; bb[2] = bv.z; bb[3] = bv.w;
        }
#pragma unroll
        for (int nt = 0; nt < 4; ++nt) {
            const int nl = wc * 64 + nt * 16 + ln;
            const int x = x0 + (nl & 31);
            const int y = y0 + (nl >> 5);
            if (x >= 100) continue;
            if (EPI == 1) {
                float v[4];
#pragma unroll
                for (int r = 0; r < 4; ++r) {
                    float t = acc[mt][nt][r] + bb[r];
                    if (ACT) t = gelu_exact(t);
                    v[r] = t;
                }
                ushort4 pk;
                pk.x = f2bf(v[0]); pk.y = f2bf(v[1]); pk.z = f2bf(v[2]); pk.w = f2bf(v[3]);
                *(ushort4*)(outcl + ((size_t)(y + OPAD) * OPW + (x + OPAD)) * COUT + ocr) = pk;
            } else {
                const int pix = y * WID + x;
#pragma unroll
                for (int r = 0; r < 4; ++r)
                    outcm[((size_t)ks * COUT + ocr + r) * HW + pix] = acc[mt][nt][r];
            }
        }
    }
}

// out = bias + res + slab0 + slab1 + slab2   (128 x HW)
__global__ void reduce3_k(const float* __restrict__ bias, const float* __restrict__ res,
                          const float* __restrict__ slab, float* __restrict__ out)
{
    const int i = blockIdx.x * blockDim.x + threadIdx.x;
    if (i >= 128 * HW) return;
    const int c = i / HW;
    out[i] = bias[c] + res[i] + slab[i] + slab[1280000 + i] + slab[2560000 + i];
}

__global__ void pad_cl_f32(const float* __restrict__ in, float* __restrict__ out)
{
    const int total = 104 * 104 * 128;
    for (int i = blockIdx.x * blockDim.x + threadIdx.x; i < total; i += gridDim.x * blockDim.x) {
        const int c = i % 128;
        const int p = i / 128;
        const int x = p % 104 - 2;
        const int y = p / 104 - 2;
        float v = 0.f;
        if (x >= 0 && x < 100 && y >= 0 && y < 100) v = in[(size_t)c * HW + y * WID + x];
        out[i] = v;
    }
}

template<int C, int PAD>
__global__ void pad_cl_cast(const float* __restrict__ in, short* __restrict__ out)
{
    constexpr int PW = 100 + 2 * PAD;
    const int total = PW * PW * C;
    for (int i = blockIdx.x * blockDim.x + threadIdx.x; i < total; i += gridDim.x * blockDim.x) {
        const int c = i % C;
        const int p = i / C;
        const int x = p % PW - PAD;
        const int y = p / PW - PAD;
        float v = 0.f;
        if (x >= 0 && x < 100 && y >= 0 && y < 100) v = in[(size_t)c * HW + y * WID + x];
        out[i] = (short)f2bf(v);
    }
}

template<int OC, int CI, int KS>
__global__ void pack_w(const float* __restrict__ w, short* __restrict__ out)
{
    const int total = OC * CI * KS * KS;
    for (int i = blockIdx.x * blockDim.x + threadIdx.x; i < total; i += gridDim.x * blockDim.x) {
        const int ic = i % CI;
        int t = i / CI;
        const int oc = t % OC;
        const int s = t / OC;
        const int ky = s / KS, kx = s % KS;
        out[i] = (short)f2bf(w[(((size_t)oc * CI + ic) * KS + ky) * KS + kx]);
    }
}

__global__ void pack_w1_f32(const float* __restrict__ w, float* __restrict__ out)
{
    const int total = 128 * 128 * 25;
    for (int i = blockIdx.x * blockDim.x + threadIdx.x; i < total; i += gridDim.x * blockDim.x) {
        const int oc = i % 128;
        int t = i / 128;
        const int ic = t % 128;
        const int s = t / 128;
        const int ky = s / 5, kx = s % 5;
        out[i] = w[(((size_t)oc * 128 + ic) * 5 + ky) * 5 + kx];
    }
}

__global__ void inorm_k(const float* __restrict__ in, float* __restrict__ out)
{
    const int c = blockIdx.x;
    const float* p = in + (size_t)c * HW;
    __shared__ float red[256];
    const int tid = threadIdx.x;

    float s = 0.f;
    for (int i = tid; i < HW; i += 256) s += p[i];
    red[tid] = s; __syncthreads();
    for (int o = 128; o > 0; o >>= 1) { if (tid < o) red[tid] += red[tid + o]; __syncthreads(); }
    const float mean = red[0] * 1e-4f;
    __syncthreads();

    float v = 0.f;
    for (int i = tid; i < HW; i += 256) { const float d = p[i] - mean; v += d * d; }
    red[tid] = v; __syncthreads();
    for (int o = 128; o > 0; o >>= 1) { if (tid < o) red[tid] += red[tid + o]; __syncthreads(); }
    const float rstd = rsqrtf(red[0] * 1e-4f + 1e-5f);

    float* op = out + (size_t)c * HW;
    for (int i = tid; i < HW; i += 256) op[i] = (p[i] - mean) * rstd;
}

__global__ void offsw_k(const float* __restrict__ qn, const float* __restrict__ bev_pos,
                        const float* __restrict__ off_w, const float* __restrict__ off_b,
                        const float* __restrict__ sw_w, const float* __restrict__ sw_b,
                        float* __restrict__ refp, float* __restrict__ swts)
{
    const int pix = blockIdx.x;
    const int tid = threadIdx.x;
    __shared__ float qv[128];
    __shared__ float swraw[32];
    qv[tid]      = qn[(size_t)tid * HW + pix];
    qv[tid + 64] = qn[(size_t)(tid + 64) * HW + pix];
    __syncthreads();

    if (tid < 24) {
        float acc = off_b[tid];
        for (int c = 0; c < 128; ++c) acc = fmaf(qv[c], off_w[tid * 128 + c], acc);
        const float s = 1.0f / (1.0f + expf(-acc));
        const int coord = tid % 3;
        const float rng = (coord < 2) ? 0.250001f : 4.000001f;
        const float v = s * rng * 2.0f - rng;
        const float lo[3]   = {-50.f, -50.f, -5.f};
        const float span[3] = {100.f, 100.f, 8.f};
        refp[pix * 24 + tid] = bev_pos[pix * 3 + coord] * span[coord] + lo[coord] + v;
    } else if (tid >= 32) {
        const int j = tid - 32;
        float acc = sw_b[j];
        for (int c = 0; c < 128; ++c) acc = fmaf(qv[c], sw_w[j * 128 + c], acc);
        swraw[j] = acc;
    }
    __syncthreads();
    if (tid < 8) {
        float m = -1e30f;
#pragma unroll
        for (int l = 0; l < 4; ++l) m = fmaxf(m, swraw[tid * 4 + l]);
        float e[4], sum = 0.f;
#pragma unroll
        for (int l = 0; l < 4; ++l) { e[l] = expf(swraw[tid * 4 + l] - m); sum += e[l]; }
        const float inv = 1.0f / sum;
#pragma unroll
        for (int l = 0; l < 4; ++l) swts[pix * 32 + tid * 4 + l] = e[l] * inv;
    }
}

__global__ void transpose_feat_k(const float* __restrict__ in, float* __restrict__ out,
                                 int Hl, int Wl)
{
    const int total = 6 * 132 * Hl * Wl;
    for (int i = blockIdx.x * blockDim.x + threadIdx.x; i < total; i += gridDim.x * blockDim.x) {
        int c = i % 132;
        int t = i / 132;
        const int x = t % Wl; t /= Wl;
        const int y = t % Hl; t /= Hl;
        const int n = t;
        out[i] = in[(((size_t)n * 132 + c) * Hl + y) * Wl + x];
    }
}

// ---------------------------------------------------------------------------
// proj_k: one wave per pixel; lanes 0..47 = (p=t/6, n=t%6). Projects once,
// ballot-compacts surviving (gx,gy) into per-(pix,p) lists (n-ascending).
// ---------------------------------------------------------------------------
__global__ __launch_bounds__(64)
void proj_k(const float* __restrict__ refp, const float* __restrict__ l2i,
            float2* __restrict__ recs, int* __restrict__ cnts)
{
    const int pix = blockIdx.x;
    const int t = threadIdx.x;
    bool keep = false;
    float gx = -2.f, gy = -2.f;
    int p = 0;
    if (t < 48) {
        p = t / 6;
        const int n = t - p * 6;
        const float X = refp[pix * 24 + p * 3 + 0];
        const float Y = refp[pix * 24 + p * 3 + 1];
        const float Z = refp[pix * 24 + p * 3 + 2];
        const float* m = l2i + n * 16;
        const float cx = m[0] * X + m[1] * Y + m[2]  * Z + m[3];
        const float cy = m[4] * X + m[5] * Y + m[6]  * Z + m[7];
        const float cz = m[8] * X + m[9] * Y + m[10] * Z + m[11];
        const bool valid = cz > 1e-5f;
        const float zz = fmaxf(cz, 1e-5f);
        gx = valid ? (cx / zz) * (2.0f / 704.0f) - 1.0f : -2.0f;
        gy = valid ? (cy / zz) * (2.0f / 256.0f) - 1.0f : -2.0f;
        // union of all per-level acceptance windows (levels re-check exactly)
        keep = (gx > -1.092f) && (gx < 1.092f) && (gy > -1.26f) && (gy < 1.26f);
    }
    const unsigned long long bm = __ballot(keep);
    if (keep) {
        const unsigned long long gmask = 0x3Full << (p * 6);
        const int slot = __popcll(bm & ((1ull << t) - 1ull) & gmask);
        recs[(size_t)pix * 48 + p * 6 + slot] = make_float2(gx, gy);
    }
    if (t < 48 && (t % 6) == 0) {
        const unsigned long long gmask = 0x3Full << (p * 6);
        cnts[pix * 8 + p] = __popcll(bm & gmask);
    }
}

// ---------------------------------------------------------------------------
// sample_k round 5: loops only valid projection records.
// ---------------------------------------------------------------------------
__global__ __launch_bounds__(128)
void sample_k(const float* __restrict__ refp, const float* __restrict__ swts,
              const float2* __restrict__ recs, const int* __restrict__ cnts,
              const float* __restrict__ fT0, const float* __restrict__ fT1,
              const float* __restrict__ fT2, const float* __restrict__ fT3,
              short* __restrict__ sfo)
{
    const int pix = blockIdx.x;
    const int tid = threadIdx.x;                   // 128
    __shared__ float rp[24], sw[32], tail[32];
    __shared__ float2 rec[48];
    __shared__ int cnt[8];
    if (tid < 24) rp[tid] = refp[pix * 24 + tid];
    if (tid < 32) sw[tid] = swts[pix * 32 + tid];
    if (tid < 48) rec[tid] = recs[(size_t)pix * 48 + tid];
    if (tid < 8)  cnt[tid] = cnts[pix * 8 + tid];
    __syncthreads();

    const float* fT[4] = {fT0, fT1, fT2, fT3};
    const int HL[4] = {32, 16, 8, 4};
    const int WL[4] = {88, 44, 22, 11};

    float acc[8], accT[8];
#pragma unroll
    for (int p = 0; p < 8; ++p) {
        float av = 0.f, aTv = 0.f;
        const int c = cnt[p];
        for (int r = 0; r < c; ++r) {
            const float gx = rec[p * 6 + r].x;
            const float gy = rec[p * 6 + r].y;
#pragma unroll
            for (int l = 0; l < 4; ++l) {
                const float wl = sw[p * 4 + l];
                const int Hl = HL[l], Wl = WL[l];
                const float fx = (gx + 1.0f) * 0.5f * (float)Wl - 0.5f;
                const float fy = (gy + 1.0f) * 0.5f * (float)Hl - 0.5f;
                if (!(fx >= -1.0f && fx < (float)Wl && fy >= -1.0f && fy < (float)Hl))
                    continue;
                const float x0f = floorf(fx), y0f = floorf(fy);
                const int x0 = (int)x0f, y0 = (int)y0f;
                const int x1 = x0 + 1, y1 = y0 + 1;
                const float wx1 = fx - x0f, wy1 = fy - y0f;
                const float wx0 = 1.0f - wx1, wy0 = 1.0f - wy1;
                const bool okx0 = (x0 >= 0), okx1 = (x1 < Wl);
                const bool oky0 = (y0 >= 0), oky1 = (y1 < Hl);
                // level bases folded in via fT[l]; n baked into record? no —
                // records only hold gx,gy; n-dependence enters via feat base:
                // recover n is impossible — so bake n into gx? NO: we must
                // keep per-record feature base.  (See recs2 below.)
                (void)okx0; (void)okx1; (void)oky0; (void)oky1;
            }
        }
        acc[p] = av; accT[p] = aTv;
    }
    // NOTE: placeholder body replaced below — real implementation in
    // sample_k2 (this kernel is unused).
    (void)fT; (void)acc; (void)accT; (void)tail; (void)sfo;
}

// Real sampling kernel: records carry the camera index packed in .x sign? No —
// separate int array recn holds n per record.
__global__ __launch_bounds__(128)
void sample_k2(const float* __restrict__ refp, const float* __restrict__ swts,
               const float2* __restrict__ recs, const int* __restrict__ recn,
               const int* __restrict__ cnts,
               const float* __restrict__ fT0, const float* __restrict__ fT1,
               const float* __restrict__ fT2, const float* __restrict__ fT3,
               short* __restrict__ sfo)
{
    const int pix = blockIdx.x;
    const int tid = threadIdx.x;                   // 128
    __shared__ float rp[24], sw[32], tail[32];
    __shared__ float2 rec[48];
    __shared__ int rn[48];
    __shared__ int cnt[8];
    if (tid < 24) rp[tid] = refp[pix * 24 + tid];
    if (tid < 32) sw[tid] = swts[pix * 32 + tid];
    if (tid < 48) { rec[tid] = recs[(size_t)pix * 48 + tid]; rn[tid] = recn[(size_t)pix * 48 + tid]; }
    if (tid < 8)  cnt[tid] = cnts[pix * 8 + tid];
    __syncthreads();

    const float* fT[4] = {fT0, fT1, fT2, fT3};
    const int HL[4] = {32, 16, 8, 4};
    const int WL[4] = {88, 44, 22, 11};

    float acc[8], accT[8];
#pragma unroll
    for (int p = 0; p < 8; ++p) {
        float av = 0.f, aTv = 0.f;
        const int c = cnt[p];
        for (int r = 0; r < c; ++r) {
            const float gx = rec[p * 6 + r].x;
            const float gy = rec[p * 6 + r].y;
            const int n = rn[p * 6 + r];
#pragma unroll
            for (int l = 0; l < 4; ++l) {
                const float wl = sw[p * 4 + l];
                const int Hl = HL[l], Wl = WL[l];
                const float fx = (gx + 1.0f) * 0.5f * (float)Wl - 0.5f;
                const float fy = (gy + 1.0f) * 0.5f * (float)Hl - 0.5f;
                if (!(fx >= -1.0f && fx < (float)Wl && fy >= -1.0f && fy < (float)Hl))
                    continue;
                const float x0f = floorf(fx), y0f = floorf(fy);
                const int x0 = (int)x0f, y0 = (int)y0f;
                const int x1 = x0 + 1, y1 = y0 + 1;
                const float wx1 = fx - x0f, wy1 = fy - y0f;
                const float wx0 = 1.0f - wx1, wy0 = 1.0f - wy1;
                const bool okx0 = (x0 >= 0), okx1 = (x1 < Wl);
                const bool oky0 = (y0 >= 0), oky1 = (y1 < Hl);
                const float* fb = fT[l] + (size_t)n * Hl * Wl * 132;
                if (okx0 && oky0) {
                    const float wt = wx0 * wy0 * wl;
                    const float* tp = fb + (size_t)(y0 * Wl + x0) * 132;
                    av = fmaf(tp[tid], wt, av);
                    if (tid < 4) aTv = fmaf(tp[128 + tid], wt, aTv);
                }
                if (okx1 && oky0) {
                    const float wt = wx1 * wy0 * wl;
                    const float* tp = fb + (size_t)(y0 * Wl + x1) * 132;
                    av = fmaf(tp[tid], wt, av);
                    if (tid < 4) aTv = fmaf(tp[128 + tid], wt, aTv);
                }
                if (okx0 && oky1) {
                    const float wt = wx0 * wy1 * wl;
                    const float* tp = fb + (size_t)(y1 * Wl + x0) * 132;
                    av = fmaf(tp[tid], wt, av);
                    if (tid < 4) aTv = fmaf(tp[128 + tid], wt, aTv);
                }
                if (okx1 && oky1) {
                    const float wt = wx1 * wy1 * wl;
                    const float* tp = fb + (size_t)(y1 * Wl + x1) * 132;
                    av = fmaf(tp[tid], wt, av);
                    if (tid < 4) aTv = fmaf(tp[128 + tid], wt, aTv);
                }
            }
        }
        acc[p] = av; accT[p] = aTv;
    }

    if (tid < 4) {
#pragma unroll
        for (int p = 0; p < 8; ++p) tail[p * 4 + tid] = accT[p];
    }
    __syncthreads();

    float sf1 = 0.f, sf2 = 0.f;
#pragma unroll
    for (int p = 0; p < 8; ++p) {
        const float dx = rp[p * 3]     - tail[p * 4 + 0];
        const float dy = rp[p * 3 + 1] - tail[p * 4 + 1];
        const float dz = rp[p * 3 + 2] - tail[p * 4 + 2];
        const float wgt = expf(-0.1f * (dx * dx + dy * dy + dz * dz));
        sf1 += acc[p];
        sf2 += acc[p] * wgt;
    }
    const int y = pix / WID, x = pix % WID;
    const size_t po = ((size_t)(y + 1) * 102 + (x + 1)) * 256;
    sfo[po + tid]       = (short)f2bf(sf1);
    sfo[po + 128 + tid] = (short)f2bf(sf2);
}

// proj_k variant that also records n
__global__ __launch_bounds__(64)
void proj_k2(const float* __restrict__ refp, const float* __restrict__ l2i,
             float2* __restrict__ recs, int* __restrict__ recn, int* __restrict__ cnts)
{
    const int pix = blockIdx.x;
    const int t = threadIdx.x;
    bool keep = false;
    float gx = -2.f, gy = -2.f;
    int p = 0, n = 0;
    if (t < 48) {
        p = t / 6;
        n = t - p * 6;
        const float X = refp[pix * 24 + p * 3 + 0];
        const float Y = refp[pix * 24 + p * 3 + 1];
        const float Z = refp[pix * 24 + p * 3 + 2];
        const float* m = l2i + n * 16;
        const float cx = m[0] * X + m[1] * Y + m[2]  * Z + m[3];
        const float cy = m[4] * X + m[5] * Y + m[6]  * Z + m[7];
        const float cz = m[8] * X + m[9] * Y + m[10] * Z + m[11];
        const bool valid = cz > 1e-5f;
        const float zz = fmaxf(cz, 1e-5f);
        gx = valid ? (cx / zz) * (2.0f / 704.0f) - 1.0f : -2.0f;
        gy = valid ? (cy / zz) * (2.0f / 256.0f) - 1.0f : -2.0f;
        keep = (gx > -1.092f) && (gx < 1.092f) && (gy > -1.26f) && (gy < 1.26f);
    }
    const unsigned long long bm = __ballot(keep);
    if (keep) {
        const unsigned long long gmask = 0x3Full << (p * 6);
        const int slot = __popcll(bm & ((1ull << t) - 1ull) & gmask);
        recs[(size_t)pix * 48 + p * 6 + slot] = make_float2(gx, gy);
        recn[(size_t)pix * 48 + p * 6 + slot] = n;
    }
    if (t < 48 && (t % 6) == 0) {
        const unsigned long long gmask = 0x3Full << (p * 6);
        cnts[pix * 8 + p] = __popcll(bm & gmask);
    }
}

// ---------------------------------------------------------------------------

extern "C" void kernel_launch(void* const* d_in, const int* in_sizes, int n_in,
                              void* d_out, int out_size, void* d_ws, size_t ws_size,
                              hipStream_t stream)
{
    const float* bev_query = (const float*)d_in[0];
    const float* bev_pos   = (const float*)d_in[1];
    const float* l2i       = (const float*)d_in[2];
    const float* feat0     = (const float*)d_in[3];
    const float* feat1     = (const float*)d_in[4];
    const float* feat2     = (const float*)d_in[5];
    const float* feat3     = (const float*)d_in[6];
    const float* in_w      = (const float*)d_in[7];
    const float* in_b      = (const float*)d_in[8];
    const float* off_w     = (const float*)d_in[9];
    const float* off_b     = (const float*)d_in[10];
    const float* sw_w      = (const float*)d_in[11];
    const float* sw_b      = (const float*)d_in[12];
    const float* mid_w1    = (const float*)d_in[13];
    const float* mid_b1    = (const float*)d_in[14];
    const float* mid_w2    = (const float*)d_in[15];
    const float* mid_b2    = (const float*)d_in[16];
    const float* mid_w3    = (const float*)d_in[17];
    const float* mid_b3    = (const float*)d_in[18];
    const float* out_w     = (const float*)d_in[19];
    const float* out_b     = (const float*)d_in[20];
    float* out = (float*)d_out;

    float* ws    = (float*)d_ws;
    float* qn    = ws;                        // 1,280,000 f
    float* tmp   = qn + 1280000;              // 1,280,000 f
    float* refp  = tmp + 1280000;             //   240,000 f
    float* swts  = refp + 240000;             //   320,000 f
    float* slab  = swts + 320000;             // 3,840,000 f  (3 K-split slabs; fT alias)
    float* wpk1f = slab + 3840000;            //   409,600 f
    short* m1U   = (short*)(wpk1f + 409600);  // 5,130,000 sh
    short* m2U   = m1U + 5130000;             // 5,345,000 sh
    short* wp_m1 = m2U + 5345000;             // 1,179,648 sh
    short* wp_m2 = wp_m1 + 1179648;           //   262,144 sh
    short* wp_m3 = wp_m2 + 262144;            //   589,824 sh
    short* wp_out= wp_m3 + 589824;            //   409,600 sh
    float2* recs = (float2*)(wp_out + 409600);//   480,000 float2 (3.84 MB)
    int*   recn  = (int*)(recs + 480000);     //   480,000 i
    int*   cnts  = recn + 480000;             //    80,000 i

    float* fT0 = slab;
    float* fT1 = fT0 + 6 * 132 * 32 * 88;
    float* fT2 = fT1 + 6 * 132 * 16 * 44;
    float* fT3 = fT2 + 6 * 132 * 8  * 22;
    float* xpadf = (float*)m1U;
    short* m1_cl = m1U;
    short* q2pad = m1U;
    short* sf_cl = m2U;
    short* m2_cl = m2U;

    const dim3 blk(256);

    // ---- weight packing ----
    hipLaunchKernelGGL(pack_w1_f32, dim3(1600), blk, 0, stream, in_w, wpk1f);
    hipLaunchKernelGGL((pack_w<512, 256, 3>), dim3(4608), blk, 0, stream, mid_w1, wp_m1);
    hipLaunchKernelGGL((pack_w<512, 512, 1>), dim3(1024), blk, 0, stream, mid_w2, wp_m2);
    hipLaunchKernelGGL((pack_w<128, 512, 3>), dim3(2304), blk, 0, stream, mid_w3, wp_m3);
    hipLaunchKernelGGL((pack_w<128, 128, 5>), dim3(1600), blk, 0, stream, out_w, wp_out);

    // ---- 1. q1 = bev_query + conv5x5_f32(bev_query) ----
    hipLaunchKernelGGL(pad_cl_f32, dim3(5411), blk, 0, stream, bev_query, xpadf);
    hipLaunchKernelGGL(conv1_f32, dim3(4, 50, 3), blk, 0, stream, wpk1f, xpadf, slab);
    hipLaunchKernelGGL(reduce3_k, dim3(5000), blk, 0, stream, in_b, bev_query, slab, tmp);
    // ---- 2. qn = inorm(q1) ----
    hipLaunchKernelGGL(inorm_k, dim3(128), blk, 0, stream, tmp, qn);
    // ---- 3. ref points + softmax weights (fp32) ----
    hipLaunchKernelGGL(offsw_k, dim3(HW), dim3(64), 0, stream,
                       qn, bev_pos, off_w, off_b, sw_w, sw_b, refp, swts);
    // ---- 3b. projection compaction ----
    hipLaunchKernelGGL(proj_k2, dim3(HW), dim3(64), 0, stream, refp, l2i, recs, recn, cnts);
    // ---- 4. feature transposes ----
    hipLaunchKernelGGL(transpose_feat_k, dim3(8713), blk, 0, stream, feat0, fT0, 32, 88);
    hipLaunchKernelGGL(transpose_feat_k, dim3(2179), blk, 0, stream, feat1, fT1, 16, 44);
    hipLaunchKernelGGL(transpose_feat_k, dim3(545),  blk, 0, stream, feat2, fT2, 8, 22);
    hipLaunchKernelGGL(transpose_feat_k, dim3(137),  blk, 0, stream, feat3, fT3, 4, 11);
    // ---- 5. sampling -> sf_cl bf16 padded(1) ----
    hipMemsetAsync(sf_cl, 0, (size_t)2663424 * 2, stream);
    hipLaunchKernelGGL(sample_k2, dim3(HW), dim3(128), 0, stream,
                       refp, swts, recs, recn, cnts, fT0, fT1, fT2, fT3, sf_cl);
    // ---- 6. m1 = gelu(conv3x3 256->512) ----
    hipLaunchKernelGGL((mfma_conv<256, 3, 512, 1, true, 0, 100, 1>), dim3(4, 25, 4), blk, 0, stream,
                       wp_m1, sf_cl, mid_b1, nullptr, m1_cl);
    // ---- 7. m2 = gelu(conv1x1 512->512) -> m2_cl padded(1) ----
    hipMemsetAsync(m2U, 0, (size_t)5326848 * 2, stream);
    hipLaunchKernelGGL((mfma_conv<512, 1, 512, 1, true, 1, 102, 1>), dim3(4, 25, 4), blk, 0, stream,
                       wp_m2, m1_cl, mid_b2, nullptr, m2_cl);
    // ---- 8. q2 = qn + conv3x3 512->128  (K-split 3, slabs) ----
    hipLaunchKernelGGL((mfma_conv<512, 3, 128, 2, false, 0, 0, 3>), dim3(1, 25, 12), blk, 0, stream,
                       wp_m3, m2_cl, mid_b3, slab, nullptr);
    hipLaunchKernelGGL(reduce3_k, dim3(5000), blk, 0, stream, mid_b3, qn, slab, tmp);
    // ---- 9. q2n = inorm(q2) ----
    hipLaunchKernelGGL(inorm_k, dim3(128), blk, 0, stream, tmp, qn);
    // ---- 10. q3 = q2n + conv5x5 bf16 (K-split 3, slabs) ----
    hipLaunchKernelGGL((pad_cl_cast<128, 2>), dim3(5411), blk, 0, stream, qn, q2pad);
    hipLaunchKernelGGL((mfma_conv<128, 5, 128, 2, false, 0, 0, 3>), dim3(1, 25, 12), blk, 0, stream,
                       wp_out, q2pad, out_b, slab, nullptr);
    hipLaunchKernelGGL(reduce3_k, dim3(5000), blk, 0, stream, out_b, qn, slab, tmp);
    // ---- 11. out = inorm(q3) ----
    hipLaunchKernelGGL(inorm_k, dim3(128), blk, 0, stream, tmp, out);
}

// Round 6
// 827.843 us; speedup vs baseline: 1.3065x; 1.0950x over previous
//
#include <hip/hip_runtime.h>
#include <cstddef>

// ---------------------------------------------------------------------------
// SegTransformerDecoder — round 6.
//  * conv1_f32 v2: 8x8 thread tile, conflict-free contiguous LDS staging,
//    channel-major padded input, KSPLIT=5, vectorized epilogue.
//  * fused red_norm (reduceN + instance-norm, register-resident),
//    offsw+proj merged, transposes merged, bf16 packs merged.
// ---------------------------------------------------------------------------

#define HW   10000
#define WID  100

typedef __attribute__((ext_vector_type(8))) __bf16 bf16x8;
typedef __attribute__((ext_vector_type(4))) float f32x4;
typedef __attribute__((ext_vector_type(4))) unsigned int uint4v;

__device__ __forceinline__ float gelu_exact(float x) {
    return 0.5f * x * (1.0f + erff(x * 0.7071067811865475f));
}
__device__ __forceinline__ unsigned short f2bf(float v) {
    unsigned int b = __float_as_uint(v);
    return (unsigned short)((b + 0x7FFFu + ((b >> 16) & 1u)) >> 16);
}
__device__ __forceinline__ bf16x8 load_frag(const short* p) {
    return __builtin_bit_cast(bf16x8, *(const uint4v*)p);
}

// ---------------------------------------------------------------------------
// conv1_f32 v2 (decision chain, exact fp32).
// input xpadP: channel-major padded(2) [128][104][104] fp32
// weights wpkf: [ky][kx][ic][oc] fp32
// block 256, tile 128oc x 128pix (4 rows x 32 cols), thread = 8oc x 8pix
// grid (4, 25, 5); z = ky; slab[z][oc][pix] store.
// ---------------------------------------------------------------------------
__global__ __launch_bounds__(256)
void conv1_f32(const float* __restrict__ wpkf, const float* __restrict__ xpadP,
               float* __restrict__ slab)
{
    __shared__ float As[2048];      // [ic 16][oc 128]
    __shared__ float Bs[2048];      // [ic 16][pix 128]
    const int t  = threadIdx.x;
    const int og = t >> 4;          // oc group (8 oc)
    const int pg = t & 15;          // pix group (8 pix)
    const int x0 = blockIdx.x * 32, y0 = blockIdx.y * 4;
    const int ky = blockIdx.z;

    // Bs staging element mapping (two passes, contiguous)
    const int e0 = t * 4, e1 = 1024 + t * 4;
    const int ica = e0 >> 7, pa = e0 & 127;
    const int icb = e1 >> 7, pb = e1 & 127;
    const int rowa = (y0 + (pa >> 5) + ky) * 104 + x0 + (pa & 31);
    const int rowb = (y0 + (pb >> 5) + ky) * 104 + x0 + (pb & 31);

    float acc[8][8];
#pragma unroll
    for (int i = 0; i < 8; ++i)
#pragma unroll
        for (int j = 0; j < 8; ++j) acc[i][j] = 0.f;

    for (int kx = 0; kx < 5; ++kx) {
        for (int ic0 = 0; ic0 < 128; ic0 += 16) {
            __syncthreads();
            const float* asrc = wpkf + (size_t)((ky * 5 + kx) * 128 + ic0) * 128;
            *(float4*)(As + e0) = *(const float4*)(asrc + e0);
            *(float4*)(As + e1) = *(const float4*)(asrc + e1);
            float4 bva, bvb;
            __builtin_memcpy(&bva, xpadP + (size_t)(ic0 + ica) * 10816 + rowa + kx, 16);
            __builtin_memcpy(&bvb, xpadP + (size_t)(ic0 + icb) * 10816 + rowb + kx, 16);
            *(float4*)(Bs + e0) = bva;
            *(float4*)(Bs + e1) = bvb;
            __syncthreads();
#pragma unroll
            for (int k = 0; k < 16; ++k) {
                float a[8], b[8];
                *(float4*)(a)     = *(float4*)(As + k * 128 + og * 8);
                *(float4*)(a + 4) = *(float4*)(As + k * 128 + og * 8 + 4);
                *(float4*)(b)     = *(float4*)(Bs + k * 128 + pg * 8);
                *(float4*)(b + 4) = *(float4*)(Bs + k * 128 + pg * 8 + 4);
#pragma unroll
                for (int i = 0; i < 8; ++i)
#pragma unroll
                    for (int j = 0; j < 8; ++j)
                        acc[i][j] = fmaf(a[i], b[j], acc[i][j]);
            }
        }
    }

    // epilogue: thread owns 8 consecutive pixels of one row, for 8 oc
    float* sl = slab + (size_t)ky * 1280000;
    const int py = y0 + (pg >> 2);
    const int px = x0 + (pg & 3) * 8;
    if (px >= 100) return;
#pragma unroll
    for (int i = 0; i < 8; ++i) {
        float* dst = sl + (size_t)(og * 8 + i) * HW + py * WID + px;
        if (px + 8 <= 100) {
            __builtin_memcpy(dst,     &acc[i][0], 16);
            __builtin_memcpy(dst + 4, &acc[i][4], 16);
        } else {
#pragma unroll
            for (int j = 0; j < 8; ++j)
                if (px + j < 100) dst[j] = acc[i][j];
        }
    }
}

// ---------------------------------------------------------------------------
// bf16 MFMA implicit-GEMM conv, 128oc x 128pix block tile (unchanged r5).
// ---------------------------------------------------------------------------
template<int CIN, int KS, int COUT, int EPI, bool ACT, int OPAD, int OPW, int KSPLIT>
__global__ __launch_bounds__(256)
void mfma_conv(const short* __restrict__ wpk, const short* __restrict__ xcl,
               const float* __restrict__ bias,
               float* __restrict__ outcm, short* __restrict__ outcl)
{
    constexpr int PW = 100 + 2 * (KS / 2);
    constexpr int CHUNK = (KS + KSPLIT - 1) / KSPLIT;
    const int lane = threadIdx.x & 63;
    const int wave = threadIdx.x >> 6;
    const int wr = wave >> 1;
    const int wc = wave & 1;
    const int lq = lane >> 4;
    const int ln = lane & 15;

    const int oc0 = blockIdx.x * 128;
    const int y0  = blockIdx.y * 4;
    const int zb  = blockIdx.z;
    const int bx  = (KSPLIT > 1) ? (zb & 3) : zb;
    const int ks  = (KSPLIT > 1) ? (zb >> 2) : 0;
    const int x0  = bx * 32;
    const int ky_lo = ks * CHUNK;
    const int ky_hi = (ky_lo + CHUNK < KS) ? ky_lo + CHUNK : KS;

    int bpix[4];
#pragma unroll
    for (int nt = 0; nt < 4; ++nt) {
        const int nl = wc * 64 + nt * 16 + ln;
        bpix[nt] = (y0 + (nl >> 5)) * PW + (x0 + (nl & 31));
    }

    f32x4 acc[4][4];
#pragma unroll
    for (int mt = 0; mt < 4; ++mt)
#pragma unroll
        for (int nt = 0; nt < 4; ++nt)
#pragma unroll
            for (int r = 0; r < 4; ++r) acc[mt][nt][r] = 0.f;

    const int arow0 = oc0 + wr * 64 + ln;

    for (int ky = ky_lo; ky < ky_hi; ++ky) {
#pragma unroll
        for (int kx = 0; kx < KS; ++kx) {
            const short* wsl = wpk + (size_t)((ky * KS + kx) * COUT) * CIN;
            const short* xsl = xcl + (size_t)(ky * PW + kx) * CIN;
            for (int ic0 = 0; ic0 < CIN; ic0 += 32) {
                bf16x8 a[4], b[4];
#pragma unroll
                for (int mt = 0; mt < 4; ++mt)
                    a[mt] = load_frag(wsl + (size_t)(arow0 + mt * 16) * CIN + ic0 + lq * 8);
#pragma unroll
                for (int nt = 0; nt < 4; ++nt)
                    b[nt] = load_frag(xsl + (size_t)bpix[nt] * CIN + ic0 + lq * 8);
#pragma unroll
                for (int mt = 0; mt < 4; ++mt)
#pragma unroll
                    for (int nt = 0; nt < 4; ++nt)
                        acc[mt][nt] = __builtin_amdgcn_mfma_f32_16x16x32_bf16(
                            a[mt], b[nt], acc[mt][nt], 0, 0, 0);
            }
        }
    }

#pragma unroll
    for (int mt = 0; mt < 4; ++mt) {
        const int ocr = oc0 + wr * 64 + mt * 16 + lq * 4;
        float bb[4];
        if (EPI == 1) {
            const float4 bv = *(const float4*)(bias + ocr);
            bb[0] = bv.x; bb[1] = bv.y; bb[2] = bv.z; bb[3] = bv.w;
        }
#pragma unroll
        for (int nt = 0; nt < 4; ++nt) {
            const int nl = wc * 64 + nt * 16 + ln;
            const int x = x0 + (nl & 31);
            const int y = y0 + (nl >> 5);
            if (x >= 100) continue;
            if (EPI == 1) {
                float v[4];
#pragma unroll
                for (int r = 0; r < 4; ++r) {
                    float t = acc[mt][nt][r] + bb[r];
                    if (ACT) t = gelu_exact(t);
                    v[r] = t;
                }
                ushort4 pk;
                pk.x = f2bf(v[0]); pk.y = f2bf(v[1]); pk.z = f2bf(v[2]); pk.w = f2bf(v[3]);
                *(ushort4*)(outcl + ((size_t)(y + OPAD) * OPW + (x + OPAD)) * COUT + ocr) = pk;
            } else {
                const int pix = y * WID + x;
#pragma unroll
                for (int r = 0; r < 4; ++r)
                    outcm[((size_t)ks * COUT + ocr + r) * HW + pix] = acc[mt][nt][r];
            }
        }
    }
}

// ---------------------------------------------------------------------------
// fused: out = inorm(bias + res + sum_z slab[z]) ; register-resident values.
// grid 128 (channel), block 256.
// ---------------------------------------------------------------------------
template<int NS>
__global__ __launch_bounds__(256)
void red_norm_k(const float* __restrict__ bias, const float* __restrict__ res,
                const float* __restrict__ slab, float* __restrict__ outp)
{
    const int c = blockIdx.x, tid = threadIdx.x;
    const size_t base = (size_t)c * HW;
    const float bc = bias[c];
    float v[40];
    float s1 = 0.f, s2 = 0.f;
#pragma unroll
    for (int k = 0; k < 40; ++k) {
        const int i = tid + k * 256;
        float x = 0.f;
        if (i < HW) {
            x = bc + res[base + i];
#pragma unroll
            for (int z = 0; z < NS; ++z) x += slab[(size_t)z * 1280000 + base + i];
            s1 += x; s2 += x * x;
        }
        v[k] = x;
    }
    __shared__ float r1[256], r2[256];
    r1[tid] = s1; r2[tid] = s2; __syncthreads();
    for (int o = 128; o > 0; o >>= 1) {
        if (tid < o) { r1[tid] += r1[tid + o]; r2[tid] += r2[tid + o]; }
        __syncthreads();
    }
    const float mean = r1[0] * 1e-4f;
    const float var  = fmaxf(r2[0] * 1e-4f - mean * mean, 0.f);
    const float rstd = rsqrtf(var + 1e-5f);
#pragma unroll
    for (int k = 0; k < 40; ++k) {
        const int i = tid + k * 256;
        if (i < HW) outp[base + i] = (v[k] - mean) * rstd;
    }
}

// fp32 channel-major [128][100][100] -> channel-major padded(2) [128][104][104]
__global__ void pad_xpad(const float* __restrict__ in, float* __restrict__ out)
{
    const int total = 128 * 104 * 104;
    for (int i = blockIdx.x * blockDim.x + threadIdx.x; i < total; i += gridDim.x * blockDim.x) {
        const int c = i / 10816;
        const int r = i % 10816;
        const int y = r / 104 - 2;
        const int x = r % 104 - 2;
        float v = 0.f;
        if (x >= 0 && x < 100 && y >= 0 && y < 100) v = in[(size_t)c * HW + y * WID + x];
        out[i] = v;
    }
}

// fp32 channel-major -> bf16 channel-last padded
template<int C, int PAD>
__global__ void pad_cl_cast(const float* __restrict__ in, short* __restrict__ out)
{
    constexpr int PW = 100 + 2 * PAD;
    const int total = PW * PW * C;
    for (int i = blockIdx.x * blockDim.x + threadIdx.x; i < total; i += gridDim.x * blockDim.x) {
        const int c = i % C;
        const int p = i / C;
        const int x = p % PW - PAD;
        const int y = p / PW - PAD;
        float v = 0.f;
        if (x >= 0 && x < 100 && y >= 0 && y < 100) v = in[(size_t)c * HW + y * WID + x];
        out[i] = (short)f2bf(v);
    }
}

// all four bf16 weight packs in one kernel: [oc][ic][ky][kx] -> [ky][kx][oc][ic]
__global__ void pack_all_bf16(const float* __restrict__ w1, const float* __restrict__ w2,
                              const float* __restrict__ w3, const float* __restrict__ w4,
                              short* __restrict__ out)
{
    const int E0 = 1179648, E1 = E0 + 262144, E2 = E1 + 589824, E3 = E2 + 409600;
    for (int i = blockIdx.x * blockDim.x + threadIdx.x; i < E3; i += gridDim.x * blockDim.x) {
        const float* w; int OC, CI, KS, j;
        if (i < E0)      { w = w1; OC = 512; CI = 256; KS = 3; j = i; }
        else if (i < E1) { w = w2; OC = 512; CI = 512; KS = 1; j = i - E0; }
        else if (i < E2) { w = w3; OC = 128; CI = 512; KS = 3; j = i - E1; }
        else             { w = w4; OC = 128; CI = 128; KS = 5; j = i - E2; }
        const int ic = j % CI;
        int t = j / CI;
        const int oc = t % OC;
        const int s = t / OC;
        const int ky = s / KS, kx = s % KS;
        out[i] = (short)f2bf(w[(((size_t)oc * CI + ic) * KS + ky) * KS + kx]);
    }
}

// fp32 [oc][ic][5][5] -> fp32 [ky][kx][ic][oc]  (conv1)
__global__ void pack_w1_f32(const float* __restrict__ w, float* __restrict__ out)
{
    const int total = 128 * 128 * 25;
    for (int i = blockIdx.x * blockDim.x + threadIdx.x; i < total; i += gridDim.x * blockDim.x) {
        const int oc = i % 128;
        int t = i / 128;
        const int ic = t % 128;
        const int s = t / 128;
        const int ky = s / 5, kx = s % 5;
        out[i] = w[(((size_t)oc * 128 + ic) * 5 + ky) * 5 + kx];
    }
}

// all four feature transposes: [n][c][y][x] -> [n][y][x][c], concatenated out
__global__ void transpose_all(const float* __restrict__ f0, const float* __restrict__ f1,
                              const float* __restrict__ f2, const float* __restrict__ f3,
                              float* __restrict__ out)
{
    const int O1 = 2230272, O2 = O1 + 557568, O3 = O2 + 139392, O4 = O3 + 34848;
    for (int i = blockIdx.x * blockDim.x + threadIdx.x; i < O4; i += gridDim.x * blockDim.x) {
        const float* f; int Hl, Wl, j;
        if (i < O1)      { f = f0; Hl = 32; Wl = 88; j = i; }
        else if (i < O2) { f = f1; Hl = 16; Wl = 44; j = i - O1; }
        else if (i < O3) { f = f2; Hl = 8;  Wl = 22; j = i - O2; }
        else             { f = f3; Hl = 4;  Wl = 11; j = i - O3; }
        const int c = j % 132;
        int t = j / 132;
        const int x = t % Wl; t /= Wl;
        const int y = t % Hl; t /= Hl;
        const int n = t;
        out[i] = f[(((size_t)n * 132 + c) * Hl + y) * Wl + x];
    }
}

// ---------------------------------------------------------------------------
// offsw + projection compaction fused. block = 64 (one wave) per pixel.
// ---------------------------------------------------------------------------
__global__ __launch_bounds__(64)
void offsw_proj(const float* __restrict__ qn, const float* __restrict__ bev_pos,
                const float* __restrict__ off_w, const float* __restrict__ off_b,
                const float* __restrict__ sw_w, const float* __restrict__ sw_b,
                const float* __restrict__ l2i,
                float* __restrict__ refp, float* __restrict__ swts,
                float2* __restrict__ recs, int* __restrict__ recn, int* __restrict__ cnts)
{
    const int pix = blockIdx.x;
    const int tid = threadIdx.x;
    __shared__ float qv[128];
    __shared__ float swraw[32];
    __shared__ float rp[24];
    qv[tid]      = qn[(size_t)tid * HW + pix];
    qv[tid + 64] = qn[(size_t)(tid + 64) * HW + pix];
    __syncthreads();

    if (tid < 24) {
        float acc = off_b[tid];
        for (int c = 0; c < 128; ++c) acc = fmaf(qv[c], off_w[tid * 128 + c], acc);
        const float s = 1.0f / (1.0f + expf(-acc));
        const int coord = tid % 3;
        const float rng = (coord < 2) ? 0.250001f : 4.000001f;
        const float v = s * rng * 2.0f - rng;
        const float lo[3]   = {-50.f, -50.f, -5.f};
        const float span[3] = {100.f, 100.f, 8.f};
        const float rv = bev_pos[pix * 3 + coord] * span[coord] + lo[coord] + v;
        refp[pix * 24 + tid] = rv;
        rp[tid] = rv;
    } else if (tid >= 32) {
        const int j = tid - 32;
        float acc = sw_b[j];
        for (int c = 0; c < 128; ++c) acc = fmaf(qv[c], sw_w[j * 128 + c], acc);
        swraw[j] = acc;
    }
    __syncthreads();
    if (tid < 8) {
        float m = -1e30f;
#pragma unroll
        for (int l = 0; l < 4; ++l) m = fmaxf(m, swraw[tid * 4 + l]);
        float e[4], sum = 0.f;
#pragma unroll
        for (int l = 0; l < 4; ++l) { e[l] = expf(swraw[tid * 4 + l] - m); sum += e[l]; }
        const float inv = 1.0f / sum;
#pragma unroll
        for (int l = 0; l < 4; ++l) swts[pix * 32 + tid * 4 + l] = e[l] * inv;
    }

    // projection + ballot compaction (one wave)
    bool keep = false;
    float gx = -2.f, gy = -2.f;
    int p = 0, n = 0;
    if (tid < 48) {
        p = tid / 6;
        n = tid - p * 6;
        const float X = rp[p * 3 + 0], Y = rp[p * 3 + 1], Z = rp[p * 3 + 2];
        const float* m = l2i + n * 16;
        const float cx = m[0] * X + m[1] * Y + m[2]  * Z + m[3];
        const float cy = m[4] * X + m[5] * Y + m[6]  * Z + m[7];
        const float cz = m[8] * X + m[9] * Y + m[10] * Z + m[11];
        const bool valid = cz > 1e-5f;
        const float zz = fmaxf(cz, 1e-5f);
        gx = valid ? (cx / zz) * (2.0f / 704.0f) - 1.0f : -2.0f;
        gy = valid ? (cy / zz) * (2.0f / 256.0f) - 1.0f : -2.0f;
        keep = (gx > -1.092f) && (gx < 1.092f) && (gy > -1.26f) && (gy < 1.26f);
    }
    const unsigned long long bm = __ballot(keep);
    if (keep) {
        const unsigned long long gmask = 0x3Full << (p * 6);
        const int slot = __popcll(bm & ((1ull << tid) - 1ull) & gmask);
        recs[(size_t)pix * 48 + p * 6 + slot] = make_float2(gx, gy);
        recn[(size_t)pix * 48 + p * 6 + slot] = n;
    }
    if (tid < 48 && (tid % 6) == 0) {
        const unsigned long long gmask = 0x3Full << (p * 6);
        cnts[pix * 8 + p] = __popcll(bm & gmask);
    }
}

// ---------------------------------------------------------------------------
// sampling over compacted records (unchanged from round 5's sample_k2)
// ---------------------------------------------------------------------------
__global__ __launch_bounds__(128)
void sample_k2(const float* __restrict__ refp, const float* __restrict__ swts,
               const float2* __restrict__ recs, const int* __restrict__ recn,
               const int* __restrict__ cnts,
               const float* __restrict__ fT0, const float* __restrict__ fT1,
               const float* __restrict__ fT2, const float* __restrict__ fT3,
               short* __restrict__ sfo)
{
    const int pix = blockIdx.x;
    const int tid = threadIdx.x;                   // 128
    __shared__ float rp[24], sw[32], tail[32];
    __shared__ float2 rec[48];
    __shared__ int rn[48];
    __shared__ int cnt[8];
    if (tid < 24) rp[tid] = refp[pix * 24 + tid];
    if (tid < 32) sw[tid] = swts[pix * 32 + tid];
    if (tid < 48) { rec[tid] = recs[(size_t)pix * 48 + tid]; rn[tid] = recn[(size_t)pix * 48 + tid]; }
    if (tid < 8)  cnt[tid] = cnts[pix * 8 + tid];
    __syncthreads();

    const float* fT[4] = {fT0, fT1, fT2, fT3};
    const int HL[4] = {32, 16, 8, 4};
    const int WL[4] = {88, 44, 22, 11};

    float acc[8], accT[8];
#pragma unroll
    for (int p = 0; p < 8; ++p) {
        float av = 0.f, aTv = 0.f;
        const int c = cnt[p];
        for (int r = 0; r < c; ++r) {
            const float gx = rec[p * 6 + r].x;
            const float gy = rec[p * 6 + r].y;
            const int n = rn[p * 6 + r];
#pragma unroll
            for (int l = 0; l < 4; ++l) {
                const float wl = sw[p * 4 + l];
                const int Hl = HL[l], Wl = WL[l];
                const float fx = (gx + 1.0f) * 0.5f * (float)Wl - 0.5f;
                const float fy = (gy + 1.0f) * 0.5f * (float)Hl - 0.5f;
                if (!(fx >= -1.0f && fx < (float)Wl && fy >= -1.0f && fy < (float)Hl))
                    continue;
                const float x0f = floorf(fx), y0f = floorf(fy);
                const int x0 = (int)x0f, y0 = (int)y0f;
                const int x1 = x0 + 1, y1 = y0 + 1;
                const float wx1 = fx - x0f, wy1 = fy - y0f;
                const float wx0 = 1.0f - wx1, wy0 = 1.0f - wy1;
                const bool okx0 = (x0 >= 0), okx1 = (x1 < Wl);
                const bool oky0 = (y0 >= 0), oky1 = (y1 < Hl);
                const float* fb = fT[l] + (size_t)n * Hl * Wl * 132;
                if (okx0 && oky0) {
                    const float wt = wx0 * wy0 * wl;
                    const float* tp = fb + (size_t)(y0 * Wl + x0) * 132;
                    av = fmaf(tp[tid], wt, av);
                    if (tid < 4) aTv = fmaf(tp[128 + tid], wt, aTv);
                }
                if (okx1 && oky0) {
                    const float wt = wx1 * wy0 * wl;
                    const float* tp = fb + (size_t)(y0 * Wl + x1) * 132;
                    av = fmaf(tp[tid], wt, av);
                    if (tid < 4) aTv = fmaf(tp[128 + tid], wt, aTv);
                }
                if (okx0 && oky1) {
                    const float wt = wx0 * wy1 * wl;
                    const float* tp = fb + (size_t)(y1 * Wl + x0) * 132;
                    av = fmaf(tp[tid], wt, av);
                    if (tid < 4) aTv = fmaf(tp[128 + tid], wt, aTv);
                }
                if (okx1 && oky1) {
                    const float wt = wx1 * wy1 * wl;
                    const float* tp = fb + (size_t)(y1 * Wl + x1) * 132;
                    av = fmaf(tp[tid], wt, av);
                    if (tid < 4) aTv = fmaf(tp[128 + tid], wt, aTv);
                }
            }
        }
        acc[p] = av; accT[p] = aTv;
    }

    if (tid < 4) {
#pragma unroll
        for (int p = 0; p < 8; ++p) tail[p * 4 + tid] = accT[p];
    }
    __syncthreads();

    float sf1 = 0.f, sf2 = 0.f;
#pragma unroll
    for (int p = 0; p < 8; ++p) {
        const float dx = rp[p * 3]     - tail[p * 4 + 0];
        const float dy = rp[p * 3 + 1] - tail[p * 4 + 1];
        const float dz = rp[p * 3 + 2] - tail[p * 4 + 2];
        const float wgt = expf(-0.1f * (dx * dx + dy * dy + dz * dz));
        sf1 += acc[p];
        sf2 += acc[p] * wgt;
    }
    const int y = pix / WID, x = pix % WID;
    const size_t po = ((size_t)(y + 1) * 102 + (x + 1)) * 256;
    sfo[po + tid]       = (short)f2bf(sf1);
    sfo[po + 128 + tid] = (short)f2bf(sf2);
}

// ---------------------------------------------------------------------------

extern "C" void kernel_launch(void* const* d_in, const int* in_sizes, int n_in,
                              void* d_out, int out_size, void* d_ws, size_t ws_size,
                              hipStream_t stream)
{
    const float* bev_query = (const float*)d_in[0];
    const float* bev_pos   = (const float*)d_in[1];
    const float* l2i       = (const float*)d_in[2];
    const float* feat0     = (const float*)d_in[3];
    const float* feat1     = (const float*)d_in[4];
    const float* feat2     = (const float*)d_in[5];
    const float* feat3     = (const float*)d_in[6];
    const float* in_w      = (const float*)d_in[7];
    const float* in_b      = (const float*)d_in[8];
    const float* off_w     = (const float*)d_in[9];
    const float* off_b     = (const float*)d_in[10];
    const float* sw_w      = (const float*)d_in[11];
    const float* sw_b      = (const float*)d_in[12];
    const float* mid_w1    = (const float*)d_in[13];
    const float* mid_b1    = (const float*)d_in[14];
    const float* mid_w2    = (const float*)d_in[15];
    const float* mid_b2    = (const float*)d_in[16];
    const float* mid_w3    = (const float*)d_in[17];
    const float* mid_b3    = (const float*)d_in[18];
    const float* out_w     = (const float*)d_in[19];
    const float* out_b     = (const float*)d_in[20];
    float* out = (float*)d_out;

    // ---- workspace layout (lifetime-aliased; ~55.8 MB) ----
    float* ws    = (float*)d_ws;
    float* qn    = ws;                       // 1,280,000
    float* refp  = qn + 1280000;             //   240,000
    float* swts  = refp + 240000;            //   320,000
    float* E     = swts + 320000;            // 6,400,000 (slab5 | fT+recs | m1_cl | slab3)
    float* F     = E + 6400000;              // 1,800,000 (xpadP+wpk1f | sf_cl | q2pad)
    float* H     = F + 1800000;              // 2,700,000 (m2_cl)
    short* wp_all= (short*)(H + 2700000);    // 2,441,216 sh

    float*  slab  = E;                       // conv1: 5 slabs; later convs: 3 slabs
    float*  fT0   = E;                       // 2,962,080 total (transposed feats)
    float*  fT1   = fT0 + 2230272;
    float*  fT2   = fT1 + 557568;
    float*  fT3   = fT2 + 139392;
    float2* recs  = (float2*)(E + 3000000);  // 480,000 f2
    int*    recn  = (int*)(E + 3960000);     // 480,000
    int*    cnts  = (int*)(E + 4440000);     //  80,000
    short*  m1_cl = (short*)E;               // 5,120,000 sh [100][100][512]
    float*  xpadP = F;                       // 1,384,448 f
    float*  wpk1f = F + 1384448;             //   409,600 f
    short*  sf_cl = (short*)F;               // 2,663,424 sh [102][102][256]
    short*  q2pad = (short*)F;               // 1,384,448 sh [104][104][128]
    short*  m2_cl = (short*)H;               // 5,326,848 sh [102][102][512]
    short*  wp_m1 = wp_all;                  // 1,179,648
    short*  wp_m2 = wp_m1 + 1179648;         //   262,144
    short*  wp_m3 = wp_m2 + 262144;          //   589,824
    short*  wp_out= wp_m3 + 589824;          //   409,600

    const dim3 blk(256);

    // ---- weight packing ----
    hipLaunchKernelGGL(pack_w1_f32, dim3(1600), blk, 0, stream, in_w, wpk1f);
    hipLaunchKernelGGL(pack_all_bf16, dim3(9536), blk, 0, stream,
                       mid_w1, mid_w2, mid_w3, out_w, wp_all);

    // ---- 1. q1 slabs = conv5x5_f32(bev_query), then qn = inorm(q1) fused ----
    hipLaunchKernelGGL(pad_xpad, dim3(5408), blk, 0, stream, bev_query, xpadP);
    hipLaunchKernelGGL(conv1_f32, dim3(4, 25, 5), blk, 0, stream, wpk1f, xpadP, slab);
    hipLaunchKernelGGL(red_norm_k<5>, dim3(128), blk, 0, stream, in_b, bev_query, slab, qn);

    // ---- 2. ref points + softmax weights + projection compaction ----
    hipLaunchKernelGGL(offsw_proj, dim3(HW), dim3(64), 0, stream,
                       qn, bev_pos, off_w, off_b, sw_w, sw_b, l2i,
                       refp, swts, recs, recn, cnts);

    // ---- 3. feature transposes (slab5 dead) ----
    hipLaunchKernelGGL(transpose_all, dim3(11571), blk, 0, stream,
                       feat0, feat1, feat2, feat3, fT0);

    // ---- 4. sampling -> sf_cl bf16 padded(1) ----
    hipMemsetAsync(sf_cl, 0, (size_t)2663424 * 2, stream);
    hipLaunchKernelGGL(sample_k2, dim3(HW), dim3(128), 0, stream,
                       refp, swts, recs, recn, cnts, fT0, fT1, fT2, fT3, sf_cl);

    // ---- 5. m1 = gelu(conv3x3 256->512) ----
    hipLaunchKernelGGL((mfma_conv<256, 3, 512, 1, true, 0, 100, 1>), dim3(4, 25, 4), blk, 0, stream,
                       wp_m1, sf_cl, mid_b1, nullptr, m1_cl);
    // ---- 6. m2 = gelu(conv1x1 512->512) -> padded(1) ----
    hipMemsetAsync(m2_cl, 0, (size_t)5326848 * 2, stream);
    hipLaunchKernelGGL((mfma_conv<512, 1, 512, 1, true, 1, 102, 1>), dim3(4, 25, 4), blk, 0, stream,
                       wp_m2, m1_cl, mid_b2, nullptr, m2_cl);
    // ---- 7. q2 = inorm(qn + conv3x3 512->128)  (K-split 3 slabs + fused norm) ----
    hipLaunchKernelGGL((mfma_conv<512, 3, 128, 2, false, 0, 0, 3>), dim3(1, 25, 12), blk, 0, stream,
                       wp_m3, m2_cl, mid_b3, slab, nullptr);
    hipLaunchKernelGGL(red_norm_k<3>, dim3(128), blk, 0, stream, mid_b3, qn, slab, qn);
    // ---- 8. q3 = inorm(qn + conv5x5 bf16) ----
    hipLaunchKernelGGL((pad_cl_cast<128, 2>), dim3(5411), blk, 0, stream, qn, q2pad);
    hipLaunchKernelGGL((mfma_conv<128, 5, 128, 2, false, 0, 0, 3>), dim3(1, 25, 12), blk, 0, stream,
                       wp_out, q2pad, out_b, slab, nullptr);
    hipLaunchKernelGGL(red_norm_k<3>, dim3(128), blk, 0, stream, out_b, qn, slab, out);
}